// Round 1
// baseline (3426.396 us; speedup 1.0000x reference)
//
#include <hip/hip_runtime.h>
#include <hip/hip_bf16.h>

typedef unsigned short u16;
using bf16x8 = __attribute__((ext_vector_type(8))) short;
using f32x4  = __attribute__((ext_vector_type(4))) float;

#define CM 2048   // fallback chunk rows
#define NC 8      // fallback chunks (CM*NC = 16384)

// pbuf offsets (canonical bf16 small params)
#define P_LN1G 0
#define P_LN1B 400
#define P_FW1  800
#define P_FB1  1600
#define P_FW2  1602
#define P_FB2  2402
#define P_LN2G 2802
#define P_LN2B 3202
#define P_GFB  3602
#define P_GBB  14402
#define P_BV   25202
#define P_BO   31602
#define P_OB   32002
#define P_END  32142

__device__ __forceinline__ u16 f2bf(float f) {
  unsigned u = __float_as_uint(f);
  unsigned r = u + 0x7FFFu + ((u >> 16) & 1u);   // RNE
  return (u16)(r >> 16);
}
__device__ __forceinline__ float bf2f(u16 h) {
  return __uint_as_float(((unsigned)h) << 16);
}

__device__ __forceinline__ void gl_lds16(const u16* g, u16* l) {
  __builtin_amdgcn_global_load_lds(
      (__attribute__((address_space(1))) void*)g,
      (__attribute__((address_space(3))) void*)l, 16, 0, 0);
}

// ---- runtime input-dtype detection: flag=1 if bf16, 0 if fp32 ----
__global__ void detect_dtype(int* flag, const void* x) {
  if (threadIdx.x == 0 && blockIdx.x == 0) {
    const u16* p = (const u16*)x;
    int cnt = 0;
    for (int i = 0; i < 64; i++) {
      int e = (p[2 * i] >> 7) & 0xFF;
      if (e >= 0x70 && e <= 0x85) cnt++;
    }
    *flag = (cnt >= 32) ? 1 : 0;
  }
}

__global__ void canon_bf(u16* __restrict__ dst, const void* __restrict__ src,
                         int n, const int* __restrict__ flag) {
  int i = blockIdx.x * 256 + threadIdx.x;
  if (i >= n) return;
  dst[i] = (*flag) ? ((const u16*)src)[i] : f2bf(((const float*)src)[i]);
}

__global__ void canon_x_rows(u16* __restrict__ dst, const void* __restrict__ src,
                             long base, int n, const int* __restrict__ flag) {
  int i = blockIdx.x * 256 + threadIdx.x;
  if (i >= n) return;
  long j = base + i;
  dst[i] = (*flag) ? ((const u16*)src)[j] : f2bf(((const float*)src)[j]);
}

__global__ void canon_f32k(float* __restrict__ dst, const void* __restrict__ src,
                           int n, const int* __restrict__ flag) {
  int i = blockIdx.x * 256 + threadIdx.x;
  if (i >= n) return;
  dst[i] = (*flag) ? bf2f(((const u16*)src)[i]) : ((const float*)src)[i];
}

// ---------------- generic bf16 GEMM: C(MxN) = A(MxK) @ Bt(NxK)^T ----------------
// EPI: 0 = store bf16(acc); 1 = store f32(acc + bias[col]); 2 = store bf16(elu(acc + bias[col]))
// CL: clamp A global pointers to aend (K-pad reads near buffer end; clamped data finite, x0)
template <int EPI, bool CL>
__global__ __launch_bounds__(256) void gemm_bt(
    const u16* __restrict__ A, const u16* __restrict__ Bt, void* __restrict__ Cv,
    const float* __restrict__ bias, int M, int N, int K, int lda, int ldb, int ldc,
    const u16* aend)
{
  __shared__ u16 lsA[128 * 32];
  __shared__ u16 lsB[128 * 32];
  const int tid = threadIdx.x;
  const int m0 = blockIdx.x * 128, n0 = blockIdx.y * 128;
  const int wave = tid >> 6, lane = tid & 63;
  const int wm = (wave >> 1) << 6, wn = (wave & 1) << 6;
  const int quad = lane >> 4, l16 = lane & 15;

  int ra = m0 + (tid >> 2);       if (ra > M - 1) ra = M - 1;
  int ra2 = m0 + 64 + (tid >> 2); if (ra2 > M - 1) ra2 = M - 1;
  int rb = n0 + (tid >> 2);       if (rb > N - 1) rb = N - 1;
  int rb2 = n0 + 64 + (tid >> 2); if (rb2 > N - 1) rb2 = N - 1;
  const u16* Ag  = A + (size_t)ra * lda + (tid & 3) * 8;
  const u16* Ag2 = A + (size_t)ra2 * lda + (tid & 3) * 8;
  const u16* Bg  = Bt + (size_t)rb * ldb + (tid & 3) * 8;
  const u16* Bg2 = Bt + (size_t)rb2 * ldb + (tid & 3) * 8;
  u16* la = lsA + tid * 8;
  u16* lb = lsB + tid * 8;

  f32x4 acc[4][4];
#pragma unroll
  for (int i = 0; i < 4; i++)
#pragma unroll
    for (int j = 0; j < 4; j++) acc[i][j] = (f32x4){0.f, 0.f, 0.f, 0.f};

  for (int k0 = 0; k0 < K; k0 += 32) {
    __syncthreads();
    const u16* pa  = Ag + k0;
    const u16* pa2 = Ag2 + k0;
    if (CL) { if (pa > aend) pa = aend; if (pa2 > aend) pa2 = aend; }
    gl_lds16(pa, la);
    gl_lds16(pa2, la + 2048);
    gl_lds16(Bg + k0, lb);
    gl_lds16(Bg2 + k0, lb + 2048);
    __syncthreads();
    bf16x8 af[4], bfv[4];
#pragma unroll
    for (int t = 0; t < 4; t++) {
      af[t]  = *(const bf16x8*)(lsA + ((wm + t * 16 + l16) << 5) + (quad << 3));
      bfv[t] = *(const bf16x8*)(lsB + ((wn + t * 16 + l16) << 5) + (quad << 3));
    }
#pragma unroll
    for (int mt = 0; mt < 4; mt++)
#pragma unroll
      for (int nt = 0; nt < 4; nt++)
        acc[mt][nt] = __builtin_amdgcn_mfma_f32_16x16x32_bf16(af[mt], bfv[nt], acc[mt][nt], 0, 0, 0);
  }

#pragma unroll
  for (int mt = 0; mt < 4; mt++)
#pragma unroll
    for (int r = 0; r < 4; r++) {
      const int row = m0 + wm + mt * 16 + quad * 4 + r;
      if (row < M) {
#pragma unroll
        for (int nt = 0; nt < 4; nt++) {
          const int col = n0 + wn + nt * 16 + l16;
          if (col < N) {
            float v = acc[mt][nt][r];
            if (EPI == 0) ((u16*)Cv)[(size_t)row * ldc + col] = f2bf(v);
            if (EPI == 1) ((float*)Cv)[(size_t)row * ldc + col] = v + bias[col];
            if (EPI == 2) {
              float p = v + bias[col];
              ((u16*)Cv)[(size_t)row * ldc + col] = f2bf(p > 0.f ? p : expm1f(p));
            }
          }
        }
      }
    }
}

// ---- split-K GEMM, fp32 atomicAdd into pre-biased float output ----
__global__ __launch_bounds__(256) void gemm_bt_sk(
    const u16* __restrict__ A, const u16* __restrict__ Bt, float* __restrict__ outf,
    int M, int N, int K, int lda, int ldb, int ldc)
{
  __shared__ u16 lsA[128 * 32];
  __shared__ u16 lsB[128 * 32];
  const int tid = threadIdx.x;
  const int m0 = blockIdx.x * 128, n0 = blockIdx.y * 128;
  const int wave = tid >> 6, lane = tid & 63;
  const int wm = (wave >> 1) << 6, wn = (wave & 1) << 6;
  const int quad = lane >> 4, l16 = lane & 15;
  const int S = K >> 5, kz = blockIdx.z, KS = gridDim.z;
  const int s0 = (S * kz) / KS, s1 = (S * (kz + 1)) / KS;

  int ra = m0 + (tid >> 2);       if (ra > M - 1) ra = M - 1;
  int ra2 = m0 + 64 + (tid >> 2); if (ra2 > M - 1) ra2 = M - 1;
  int rb = n0 + (tid >> 2);       if (rb > N - 1) rb = N - 1;
  int rb2 = n0 + 64 + (tid >> 2); if (rb2 > N - 1) rb2 = N - 1;
  const u16* Ag  = A + (size_t)ra * lda + (tid & 3) * 8;
  const u16* Ag2 = A + (size_t)ra2 * lda + (tid & 3) * 8;
  const u16* Bg  = Bt + (size_t)rb * ldb + (tid & 3) * 8;
  const u16* Bg2 = Bt + (size_t)rb2 * ldb + (tid & 3) * 8;
  u16* la = lsA + tid * 8;
  u16* lb = lsB + tid * 8;

  f32x4 acc[4][4];
#pragma unroll
  for (int i = 0; i < 4; i++)
#pragma unroll
    for (int j = 0; j < 4; j++) acc[i][j] = (f32x4){0.f, 0.f, 0.f, 0.f};

  for (int s = s0; s < s1; ++s) {
    const int k0 = s << 5;
    __syncthreads();
    gl_lds16(Ag + k0, la);
    gl_lds16(Ag2 + k0, la + 2048);
    gl_lds16(Bg + k0, lb);
    gl_lds16(Bg2 + k0, lb + 2048);
    __syncthreads();
    bf16x8 af[4], bfv[4];
#pragma unroll
    for (int t = 0; t < 4; t++) {
      af[t]  = *(const bf16x8*)(lsA + ((wm + t * 16 + l16) << 5) + (quad << 3));
      bfv[t] = *(const bf16x8*)(lsB + ((wn + t * 16 + l16) << 5) + (quad << 3));
    }
#pragma unroll
    for (int mt = 0; mt < 4; mt++)
#pragma unroll
      for (int nt = 0; nt < 4; nt++)
        acc[mt][nt] = __builtin_amdgcn_mfma_f32_16x16x32_bf16(af[mt], bfv[nt], acc[mt][nt], 0, 0, 0);
  }

#pragma unroll
  for (int mt = 0; mt < 4; mt++)
#pragma unroll
    for (int r = 0; r < 4; r++) {
      const int row = m0 + wm + mt * 16 + quad * 4 + r;
      if (row < M) {
#pragma unroll
        for (int nt = 0; nt < 4; nt++) {
          const int col = n0 + wn + nt * 16 + l16;
          if (col < N) atomicAdd(&outf[(size_t)row * ldc + col], acc[mt][nt][r]);
        }
      }
    }
}

// ---------------- helpers ----------------
__global__ __launch_bounds__(256) void transpose_bf(
    u16* __restrict__ dst, const void* __restrict__ src, int SR, int SC, int DR, int DC,
    const int* __restrict__ flag)
{
  __shared__ u16 t[32][33];
  const int fl = *flag;
  const int tx = threadIdx.x & 31, ty = threadIdx.x >> 5;
  const int j0 = blockIdx.x << 5;
  const int i0 = blockIdx.y << 5;
#pragma unroll
  for (int s = 0; s < 32; s += 8) {
    int sr = j0 + ty + s, sc = i0 + tx;
    u16 v = 0;
    if (sr < SR && sc < SC) {
      size_t idx = (size_t)sr * SC + sc;
      v = fl ? ((const u16*)src)[idx] : f2bf(((const float*)src)[idx]);
    }
    t[ty + s][tx] = v;
  }
  __syncthreads();
#pragma unroll
  for (int s = 0; s < 32; s += 8) {
    int dr = i0 + ty + s, dc = j0 + tx;
    if (dr < DR && dc < DC) dst[(size_t)dr * DC + dc] = t[tx][ty + s];
  }
}

__global__ void build_outT(u16* __restrict__ dst, const void* __restrict__ ow,
                           const int* __restrict__ flag) {
  const int fl = *flag;
  int idx = blockIdx.x * 256 + threadIdx.x;
  if (idx >= 140 * 7264) return;
  int o = idx / 7264, c = idx - o * 7264;
  long si = -1;
  if (c < 3600) si = (long)c * 140 + o;
  else if (c >= 3616 && c < 5416) si = (long)(c - 16) * 140 + o;
  else if (c >= 5440 && c < 7240) si = (long)(c - 40) * 140 + o;
  u16 v = 0;
  if (si >= 0) v = fl ? ((const u16*)ow)[si] : f2bf(((const float*)ow)[si]);
  dst[idx] = v;
}

__global__ void zero_u32(unsigned* p, int n) {
  int i = blockIdx.x * 256 + threadIdx.x;
  if (i < n) p[i] = 0;
}

__global__ void zero_catpads(u16* cat, int rows) {
  int idx = blockIdx.x * 256 + threadIdx.x;
  if (idx >= rows * 64) return;
  int b = idx >> 6, t = idx & 63;
  int col = t < 16 ? 3600 + t : (t < 40 ? 5400 + t : 7200 + t);
  cat[(size_t)b * 7264 + col] = 0;
}

// initialize fp32 output with out_b broadcast
__global__ void init_outf(float* __restrict__ outf, const u16* __restrict__ pbuf) {
  int i = blockIdx.x * 256 + threadIdx.x;
  if (i < 16384 * 140) outf[i] = bf2f(pbuf[P_OB + i % 140]);
}

__device__ __forceinline__ void block_sum2(float& a, float& b, float* red, int t) {
#pragma unroll
  for (int o = 32; o > 0; o >>= 1) { a += __shfl_down(a, o, 64); b += __shfl_down(b, o, 64); }
  __syncthreads();
  if ((t & 63) == 0) { red[t >> 6] = a; red[4 + (t >> 6)] = b; }
  __syncthreads();
  a = red[0] + red[1] + red[2] + red[3];
  b = red[4] + red[5] + red[6] + red[7];
}

__global__ __launch_bounds__(256) void c0_kernel(float* c0, const u16* __restrict__ WoT,
                                                 const u16* __restrict__ pbuf) {
  __shared__ float red[8];
  int d = blockIdx.x, t = threadIdx.x;
  const u16* row = WoT + (size_t)d * 6400;
  const u16* bv = pbuf + P_BV;
  float s = 0.f;
  for (int j = t; j < 6400; j += 256) s += bf2f(bv[j]) * bf2f(row[j]);
  float dummy = 0.f;
  block_sum2(s, dummy, red, t);
  if (t == 0) c0[d] = s + bf2f(pbuf[P_BO + d]);
}

// per row: copy x row into flat; compute enc -> flat[,1200:1600]
__global__ __launch_bounds__(256) void enc_rows(
    const u16* __restrict__ xc, const float* __restrict__ attn,
    const u16* __restrict__ pbuf, u16* __restrict__ flatc, int r0)
{
  __shared__ float red[8];
  const int li = blockIdx.x, t = threadIdx.x;
  const int gr = r0 + li;
  const u16* xr = xc + (size_t)li * 1200;
  u16* fr = flatc + (size_t)li * 1600;
  if (t < 150) ((uint4*)fr)[t] = ((const uint4*)xr)[t];   // cols [0,1200)
  if (gr == 0) {
    if (t < 50) ((uint4*)(fr + 1200))[t] = ((const uint4*)(xr + 800))[t];  // output[0]=x[0,2,:]
    return;
  }
  const u16* xe = xr + 800;
  const float* at = attn + (size_t)li * 400;
  const u16 *g1 = pbuf + P_LN1G, *b1 = pbuf + P_LN1B, *fw1 = pbuf + P_FW1,
            *fb1v = pbuf + P_FB1, *fw2 = pbuf + P_FW2, *fb2v = pbuf + P_FB2,
            *g2 = pbuf + P_LN2G, *b2 = pbuf + P_LN2B;
  const int i1 = t + 256;
  float a0 = bf2f(xe[t]) + at[t];
  float a1 = 0.f;
  if (i1 < 400) a1 = bf2f(xe[i1]) + at[i1];
  float s = a0 + a1, ss = a0 * a0 + a1 * a1;
  block_sum2(s, ss, red, t);
  float mean = s * (1.f / 400.f);
  float var = ss * (1.f / 400.f) - mean * mean;
  float rstd = rsqrtf(var + 1e-6f);
  float o0 = (a0 - mean) * rstd * bf2f(g1[t]) + bf2f(b1[t]);
  float o1 = 0.f;
  if (i1 < 400) o1 = (a1 - mean) * rstd * bf2f(g1[i1]) + bf2f(b1[i1]);
  float d0 = o0 * bf2f(fw1[2 * t]), d1 = o0 * bf2f(fw1[2 * t + 1]);
  if (i1 < 400) { d0 += o1 * bf2f(fw1[2 * i1]); d1 += o1 * bf2f(fw1[2 * i1 + 1]); }
  block_sum2(d0, d1, red, t);
  float t0 = d0 + bf2f(fb1v[0]); t0 = t0 > 0.f ? t0 : 0.f;
  float t1 = d1 + bf2f(fb1v[1]); t1 = t1 > 0.f ? t1 : 0.f;
  float c0v = o0 + t0 * bf2f(fw2[t]) + t1 * bf2f(fw2[400 + t]) + bf2f(fb2v[t]);
  float c1v = 0.f;
  if (i1 < 400) c1v = o1 + t0 * bf2f(fw2[i1]) + t1 * bf2f(fw2[400 + i1]) + bf2f(fb2v[i1]);
  s = c0v + c1v; ss = c0v * c0v + c1v * c1v;
  block_sum2(s, ss, red, t);
  mean = s * (1.f / 400.f);
  var = ss * (1.f / 400.f) - mean * mean;
  rstd = rsqrtf(var + 1e-6f);
  u16* dr = fr + 1200;
  dr[t] = f2bf((c0v - mean) * rstd * bf2f(g2[t]) + bf2f(b2[t]));
  if (i1 < 400) dr[i1] = f2bf((c1v - mean) * rstd * bf2f(g2[i1]) + bf2f(b2[i1]));
}

// GRU nonlinearity: h = (1-sigmoid(xz+bz0+bz1))*elu(xh+bh0 + sigmoid(xr+br0+br1)*bh1)
// ldg parameterized so fwd/bwd halves of a merged [rows x 10800] G can be consumed.
__global__ __launch_bounds__(256) void gru_act(
    const u16* __restrict__ G, int ldg, const u16* __restrict__ pbuf, int boff,
    u16* __restrict__ cat, int off, int rows)
{
  int idx = blockIdx.x * 256 + threadIdx.x;
  if (idx >= rows * 1800) return;
  int b = idx / 1800, u = idx - b * 1800;
  const u16* g = G + (size_t)b * ldg;
  const u16* B = pbuf + boff;
  float xz = bf2f(g[u]) + bf2f(B[u]) + bf2f(B[5400 + u]);
  float xr = bf2f(g[1800 + u]) + bf2f(B[1800 + u]) + bf2f(B[7200 + u]);
  float xh = bf2f(g[3600 + u]) + bf2f(B[3600 + u]);
  float rh = bf2f(B[9000 + u]);
  float z = 1.f / (1.f + expf(-xz));
  float r = 1.f / (1.f + expf(-xr));
  float pre = xh + r * rh;
  float hh = pre > 0.f ? pre : expm1f(pre);
  cat[(size_t)b * 7264 + off + u] = f2bf((1.f - z) * hh);
}

extern "C" void kernel_launch(void* const* d_in, const int* in_sizes, int n_in,
                              void* d_out, int out_size, void* d_ws, size_t ws_size,
                              hipStream_t stream) {
  // Input index maps: dict order (setup_inputs insertion) vs signature order.
  // Disambiguate via in_sizes[15]: dict -> gru_fk (8,640,000), sig -> ln2_g (400).
  static const int MAP_DICT[22] = {5,6,7,8, 9,10,11,12,13,14, 15,17,18,20, 21,22,23,24, 25,26, 27,28};
  static const int MAP_SIG[22]  = {5,6,7,8, 10,11,12,13,14,16, 17,19,20,22, 23,24,25,26, 27,28, 9,15};
  const int* MAP = (in_sizes[15] > 100000) ? MAP_DICT : MAP_SIG;

  const void* x    = d_in[0];
  const void* Wv   = d_in[MAP[0]];
  const void* bv   = d_in[MAP[1]];
  const void* Wo   = d_in[MAP[2]];
  const void* bo   = d_in[MAP[3]];
  const void* ln1b = d_in[MAP[4]];
  const void* fw1  = d_in[MAP[5]];
  const void* fb1  = d_in[MAP[6]];
  const void* fw2  = d_in[MAP[7]];
  const void* fb2  = d_in[MAP[8]];
  const void* ln2b = d_in[MAP[9]];
  const void* gfk  = d_in[MAP[10]];
  const void* gfb  = d_in[MAP[11]];
  const void* gbk  = d_in[MAP[12]];
  const void* gbb  = d_in[MAP[13]];
  const void* d2w  = d_in[MAP[14]];
  const void* d2b  = d_in[MAP[15]];
  const void* d4w  = d_in[MAP[16]];
  const void* d4b  = d_in[MAP[17]];
  const void* ow   = d_in[MAP[18]];
  const void* ob   = d_in[MAP[19]];
  const void* ln1g = d_in[MAP[20]];
  const void* ln2g = d_in[MAP[21]];
  float* outf = (float*)d_out;   // reference output dtype is float32

  unsigned char* base = (unsigned char*)d_ws;
  size_t off = 0;
  auto take = [&](size_t bytes) -> void* {
    void* p = base + off;
    off += (bytes + 255) & ~(size_t)255;
    return p;
  };
  // persistent
  // NOTE: KfT size 5400*1600*2 = 17,280,000 is 256-aligned, so KbT is exactly
  // contiguous after KfT -> KfT doubles as the merged [10800 x 1600] GRU weight.
  u16*   KfT   = (u16*)take((size_t)5400 * 1600 * 2);
  u16*   KbT   = (u16*)take((size_t)5400 * 1600 * 2);
  u16*   d2T   = (u16*)take((size_t)1800 * 3616 * 2);
  u16*   d4T   = (u16*)take((size_t)1800 * 1824 * 2);
  u16*   outT  = (u16*)take((size_t)140 * 7264 * 2);
  u16*   WoT   = (u16*)take((size_t)400 * 6400 * 2);
  u16*   MT    = (u16*)take((size_t)400 * 416 * 2);
  u16*   pbuf  = (u16*)take((size_t)P_END * 2);
  int*   flag  = (int*)take(256);
  float* c0    = (float*)take(400 * 4);
  float* d2bf  = (float*)take(1800 * 4);
  float* d4bf  = (float*)take(1800 * 4);

  // BIG path: full 16384-row cat + flat, merged GRU in 4 chunks of 4096.
  // Needs ~441 MB total; gate with margin. Fallback is byte-identical to the
  // previously verified per-chunk kernel.
  const bool BIG = ws_size >= ((size_t)450 << 20);

  u16 *flatc, *Gc, *catc;
  if (BIG) {
    flatc = (u16*)take((size_t)16384 * 1600 * 2);   // full flat
    Gc    = (u16*)take((size_t)4096 * 10800 * 2);   // merged fwd+bwd gates, chunk of 4096
    catc  = (u16*)take((size_t)16384 * 7264 * 2);   // full cat
  } else {
    flatc = (u16*)take((size_t)CM * 1600 * 2);
    Gc    = (u16*)take((size_t)CM * 5400 * 2);
    catc  = (u16*)take((size_t)CM * 7264 * 2);
  }
  // overlays (lifetimes disjoint)
  float* attnc;
  u16*   xc;
  u16*   Wvc = catc;   // prep-only, precedes any x canon / catpad writes
  if (BIG) {
    xc    = catc;                                        // 16384*1200*2 = 39,321,600 B
    attnc = (float*)((unsigned char*)catc + 39321600);   // 16384*400*4 = 26,214,400 B
  } else {
    attnc = (float*)Gc;                                  // CM*400*4
    xc    = (u16*)((unsigned char*)Gc + 3276800);        // CM*1200*2
  }

  // ---- dtype detection + canonicalization ----
  detect_dtype<<<1, 64, 0, stream>>>(flag, x);
  canon_bf<<<2, 256, 0, stream>>>(pbuf + P_LN1G, ln1g, 400, flag);
  canon_bf<<<2, 256, 0, stream>>>(pbuf + P_LN1B, ln1b, 400, flag);
  canon_bf<<<4, 256, 0, stream>>>(pbuf + P_FW1, fw1, 800, flag);
  canon_bf<<<1, 256, 0, stream>>>(pbuf + P_FB1, fb1, 2, flag);
  canon_bf<<<4, 256, 0, stream>>>(pbuf + P_FW2, fw2, 800, flag);
  canon_bf<<<2, 256, 0, stream>>>(pbuf + P_FB2, fb2, 400, flag);
  canon_bf<<<2, 256, 0, stream>>>(pbuf + P_LN2G, ln2g, 400, flag);
  canon_bf<<<2, 256, 0, stream>>>(pbuf + P_LN2B, ln2b, 400, flag);
  canon_bf<<<43, 256, 0, stream>>>(pbuf + P_GFB, gfb, 10800, flag);
  canon_bf<<<43, 256, 0, stream>>>(pbuf + P_GBB, gbb, 10800, flag);
  canon_bf<<<25, 256, 0, stream>>>(pbuf + P_BV, bv, 6400, flag);
  canon_bf<<<2, 256, 0, stream>>>(pbuf + P_BO, bo, 400, flag);
  canon_bf<<<1, 256, 0, stream>>>(pbuf + P_OB, ob, 140, flag);
  canon_f32k<<<8, 256, 0, stream>>>(d2bf, d2b, 1800, flag);
  canon_f32k<<<8, 256, 0, stream>>>(d4bf, d4b, 1800, flag);

  // ---- weight prep ----
  transpose_bf<<<dim3(50, 169), 256, 0, stream>>>(KfT, gfk, 1600, 5400, 5400, 1600, flag);
  transpose_bf<<<dim3(50, 169), 256, 0, stream>>>(KbT, gbk, 1600, 5400, 5400, 1600, flag);
  transpose_bf<<<dim3(113, 57), 256, 0, stream>>>(d2T, d2w, 3600, 1800, 1800, 3616, flag);
  transpose_bf<<<dim3(57, 57), 256, 0, stream>>>(d4T, d4w, 1800, 1800, 1800, 1824, flag);
  transpose_bf<<<dim3(200, 13), 256, 0, stream>>>(WoT, Wo, 6400, 400, 400, 6400, flag);
  build_outT<<<(140 * 7264 + 255) / 256, 256, 0, stream>>>(outT, ow, flag);
  init_outf<<<(16384 * 140 + 255) / 256, 256, 0, stream>>>(outf, pbuf);
  c0_kernel<<<400, 256, 0, stream>>>(c0, WoT, pbuf);

  // MT = (Wv@Wo)^T  (Wvc overlays catc -> must precede x canon / zero_catpads)
  canon_bf<<<10000, 256, 0, stream>>>(Wvc, Wv, 2560000, flag);
  zero_u32<<<(83200 + 255) / 256, 256, 0, stream>>>((unsigned*)MT, 83200);
  gemm_bt<0, false><<<dim3(4, 4), 256, 0, stream>>>(WoT, Wvc, MT, nullptr,
      400, 400, 6400, 6400, 6400, 416, nullptr);

  if (BIG) {
    // full-M front end: canon x once, attn once (512 blocks), enc once
    canon_x_rows<<<(16384 * 1200 + 255) / 256, 256, 0, stream>>>(
        xc, x, 0L, 16384 * 1200, flag);
    gemm_bt<1, true><<<dim3(128, 4), 256, 0, stream>>>(
        xc + 800, MT, attnc, c0, 16384, 400, 416, 1200, 416, 400,
        xc + (size_t)16384 * 1200 - 8);
    enc_rows<<<16384, 256, 0, stream>>>(xc, attnc, pbuf, flatc, 0);
    // xc/attnc dead from here; catc region becomes cat
    zero_catpads<<<(16384 * 64 + 255) / 256, 256, 0, stream>>>(catc, 16384);
    // merged GRU (fwd||bwd weights contiguous): N=10800, grid 32x85 = 2720 blocks
    for (int c = 0; c < 4; ++c) {
      const size_t r0 = (size_t)c * 4096;
      gemm_bt<0, false><<<dim3(32, 85), 256, 0, stream>>>(
          flatc + r0 * 1600, KfT, Gc, nullptr, 4096, 10800, 1600, 1600, 1600, 10800, nullptr);
      gru_act<<<(4096 * 1800 + 255) / 256, 256, 0, stream>>>(
          Gc, 10800, pbuf, P_GFB, catc + r0 * 7264, 0, 4096);
      gru_act<<<(4096 * 1800 + 255) / 256, 256, 0, stream>>>(
          Gc + 5400, 10800, pbuf, P_GBB, catc + r0 * 7264, 1800, 4096);
    }
    // full-M tail: d2/d4 1920 blocks each, out 2048 blocks
    gemm_bt<2, false><<<dim3(128, 15), 256, 0, stream>>>(
        catc, d2T, catc + 3616, d2bf, 16384, 1800, 3616, 7264, 3616, 7264, nullptr);
    gemm_bt<2, false><<<dim3(128, 15), 256, 0, stream>>>(
        catc + 3616, d4T, catc + 5440, d4bf, 16384, 1800, 1824, 7264, 1824, 7264, nullptr);
    gemm_bt_sk<<<dim3(128, 2, 8), 256, 0, stream>>>(
        catc, outT, outf, 16384, 140, 7264, 7264, 7264, 140);
  } else {
    // fallback: previously verified per-chunk path, unchanged
    zero_catpads<<<(CM * 64 + 255) / 256, 256, 0, stream>>>(catc, CM);
    for (int c = 0; c < NC; ++c) {
      const int r0 = c * CM;
      canon_x_rows<<<(CM * 1200 + 255) / 256, 256, 0, stream>>>(
          xc, x, (long)r0 * 1200, CM * 1200, flag);
      gemm_bt<1, true><<<dim3(CM / 128, 4), 256, 0, stream>>>(
          xc + 800, MT, attnc, c0, CM, 400, 416, 1200, 416, 400,
          xc + (size_t)CM * 1200 - 8);
      enc_rows<<<CM, 256, 0, stream>>>(xc, attnc, pbuf, flatc, r0);
      gemm_bt<0, false><<<dim3(CM / 128, 43), 256, 0, stream>>>(
          flatc, KfT, Gc, nullptr, CM, 5400, 1600, 1600, 1600, 5400, nullptr);
      gru_act<<<(CM * 1800 + 255) / 256, 256, 0, stream>>>(
          Gc, 5400, pbuf, P_GFB, catc, 0, CM);
      gemm_bt<0, false><<<dim3(CM / 128, 43), 256, 0, stream>>>(
          flatc, KbT, Gc, nullptr, CM, 5400, 1600, 1600, 1600, 5400, nullptr);
      gru_act<<<(CM * 1800 + 255) / 256, 256, 0, stream>>>(
          Gc, 5400, pbuf, P_GBB, catc, 1800, CM);
      gemm_bt<2, false><<<dim3(CM / 128, 15), 256, 0, stream>>>(
          catc, d2T, catc + 3616, d2bf, CM, 1800, 3616, 7264, 3616, 7264, nullptr);
      gemm_bt<2, false><<<dim3(CM / 128, 15), 256, 0, stream>>>(
          catc + 3616, d4T, catc + 5440, d4bf, CM, 1800, 1824, 7264, 1824, 7264, nullptr);
      gemm_bt_sk<<<dim3(CM / 128, 2, 8), 256, 0, stream>>>(
          catc, outT, outf + (size_t)r0 * 140, CM, 140, 7264, 7264, 7264, 140);
    }
  }
}

// Round 2
// 2445.014 us; speedup vs baseline: 1.4014x; 1.4014x over previous
//
#include <hip/hip_runtime.h>
#include <hip/hip_bf16.h>

typedef unsigned short u16;
using bf16x8 = __attribute__((ext_vector_type(8))) short;
using f32x4  = __attribute__((ext_vector_type(4))) float;

#define CM 2048   // fallback chunk rows
#define NC 8      // fallback chunks (CM*NC = 16384)

// pbuf offsets (canonical bf16 small params)
#define P_LN1G 0
#define P_LN1B 400
#define P_FW1  800
#define P_FB1  1600
#define P_FW2  1602
#define P_FB2  2402
#define P_LN2G 2802
#define P_LN2B 3202
#define P_GFB  3602
#define P_GBB  14402
#define P_BV   25202
#define P_BO   31602
#define P_OB   32002
#define P_END  32142

__device__ __forceinline__ u16 f2bf(float f) {
  unsigned u = __float_as_uint(f);
  unsigned r = u + 0x7FFFu + ((u >> 16) & 1u);   // RNE
  return (u16)(r >> 16);
}
__device__ __forceinline__ float bf2f(u16 h) {
  return __uint_as_float(((unsigned)h) << 16);
}

__device__ __forceinline__ void gl_lds16(const u16* g, u16* l) {
  __builtin_amdgcn_global_load_lds(
      (__attribute__((address_space(1))) void*)g,
      (__attribute__((address_space(3))) void*)l, 16, 0, 0);
}

// ---- runtime input-dtype detection: flag=1 if bf16, 0 if fp32 ----
__global__ void detect_dtype(int* flag, const void* x) {
  if (threadIdx.x == 0 && blockIdx.x == 0) {
    const u16* p = (const u16*)x;
    int cnt = 0;
    for (int i = 0; i < 64; i++) {
      int e = (p[2 * i] >> 7) & 0xFF;
      if (e >= 0x70 && e <= 0x85) cnt++;
    }
    *flag = (cnt >= 32) ? 1 : 0;
  }
}

__global__ void canon_bf(u16* __restrict__ dst, const void* __restrict__ src,
                         int n, const int* __restrict__ flag) {
  int i = blockIdx.x * 256 + threadIdx.x;
  if (i >= n) return;
  dst[i] = (*flag) ? ((const u16*)src)[i] : f2bf(((const float*)src)[i]);
}

__global__ void canon_x_rows(u16* __restrict__ dst, const void* __restrict__ src,
                             long base, int n, const int* __restrict__ flag) {
  int i = blockIdx.x * 256 + threadIdx.x;
  if (i >= n) return;
  long j = base + i;
  dst[i] = (*flag) ? ((const u16*)src)[j] : f2bf(((const float*)src)[j]);
}

__global__ void canon_f32k(float* __restrict__ dst, const void* __restrict__ src,
                           int n, const int* __restrict__ flag) {
  int i = blockIdx.x * 256 + threadIdx.x;
  if (i >= n) return;
  dst[i] = (*flag) ? bf2f(((const u16*)src)[i]) : ((const float*)src)[i];
}

__global__ void f32_to_bf(u16* __restrict__ dst, const float* __restrict__ src, int n) {
  int i = blockIdx.x * 256 + threadIdx.x;
  if (i < n) dst[i] = f2bf(src[i]);
}

// ---------------- generic bf16 GEMM: C(MxN) = A(MxK) @ Bt(NxK)^T ----------------
// EPI: 0 = store bf16(acc); 1 = store f32(acc + bias[col]); 2 = store bf16(elu(acc + bias[col]))
// CL: clamp A global pointers to aend (K-pad reads near buffer end; clamped data finite, x0)
template <int EPI, bool CL>
__global__ __launch_bounds__(256) void gemm_bt(
    const u16* __restrict__ A, const u16* __restrict__ Bt, void* __restrict__ Cv,
    const float* __restrict__ bias, int M, int N, int K, int lda, int ldb, int ldc,
    const u16* aend)
{
  __shared__ u16 lsA[128 * 32];
  __shared__ u16 lsB[128 * 32];
  const int tid = threadIdx.x;
  const int m0 = blockIdx.x * 128, n0 = blockIdx.y * 128;
  const int wave = tid >> 6, lane = tid & 63;
  const int wm = (wave >> 1) << 6, wn = (wave & 1) << 6;
  const int quad = lane >> 4, l16 = lane & 15;

  int ra = m0 + (tid >> 2);       if (ra > M - 1) ra = M - 1;
  int ra2 = m0 + 64 + (tid >> 2); if (ra2 > M - 1) ra2 = M - 1;
  int rb = n0 + (tid >> 2);       if (rb > N - 1) rb = N - 1;
  int rb2 = n0 + 64 + (tid >> 2); if (rb2 > N - 1) rb2 = N - 1;
  const u16* Ag  = A + (size_t)ra * lda + (tid & 3) * 8;
  const u16* Ag2 = A + (size_t)ra2 * lda + (tid & 3) * 8;
  const u16* Bg  = Bt + (size_t)rb * ldb + (tid & 3) * 8;
  const u16* Bg2 = Bt + (size_t)rb2 * ldb + (tid & 3) * 8;
  u16* la = lsA + tid * 8;
  u16* lb = lsB + tid * 8;

  f32x4 acc[4][4];
#pragma unroll
  for (int i = 0; i < 4; i++)
#pragma unroll
    for (int j = 0; j < 4; j++) acc[i][j] = (f32x4){0.f, 0.f, 0.f, 0.f};

  for (int k0 = 0; k0 < K; k0 += 32) {
    __syncthreads();
    const u16* pa  = Ag + k0;
    const u16* pa2 = Ag2 + k0;
    if (CL) { if (pa > aend) pa = aend; if (pa2 > aend) pa2 = aend; }
    gl_lds16(pa, la);
    gl_lds16(pa2, la + 2048);
    gl_lds16(Bg + k0, lb);
    gl_lds16(Bg2 + k0, lb + 2048);
    __syncthreads();
    bf16x8 af[4], bfv[4];
#pragma unroll
    for (int t = 0; t < 4; t++) {
      af[t]  = *(const bf16x8*)(lsA + ((wm + t * 16 + l16) << 5) + (quad << 3));
      bfv[t] = *(const bf16x8*)(lsB + ((wn + t * 16 + l16) << 5) + (quad << 3));
    }
#pragma unroll
    for (int mt = 0; mt < 4; mt++)
#pragma unroll
      for (int nt = 0; nt < 4; nt++)
        acc[mt][nt] = __builtin_amdgcn_mfma_f32_16x16x32_bf16(af[mt], bfv[nt], acc[mt][nt], 0, 0, 0);
  }

#pragma unroll
  for (int mt = 0; mt < 4; mt++)
#pragma unroll
    for (int r = 0; r < 4; r++) {
      const int row = m0 + wm + mt * 16 + quad * 4 + r;
      if (row < M) {
#pragma unroll
        for (int nt = 0; nt < 4; nt++) {
          const int col = n0 + wn + nt * 16 + l16;
          if (col < N) {
            float v = acc[mt][nt][r];
            if (EPI == 0) ((u16*)Cv)[(size_t)row * ldc + col] = f2bf(v);
            if (EPI == 1) ((float*)Cv)[(size_t)row * ldc + col] = v + bias[col];
            if (EPI == 2) {
              float p = v + bias[col];
              ((u16*)Cv)[(size_t)row * ldc + col] = f2bf(p > 0.f ? p : expm1f(p));
            }
          }
        }
      }
    }
}

// ---- split-K GEMM, fp32 atomicAdd into pre-initialized float output ----
__global__ __launch_bounds__(256) void gemm_bt_sk(
    const u16* __restrict__ A, const u16* __restrict__ Bt, float* __restrict__ outf,
    int M, int N, int K, int lda, int ldb, int ldc)
{
  __shared__ u16 lsA[128 * 32];
  __shared__ u16 lsB[128 * 32];
  const int tid = threadIdx.x;
  const int m0 = blockIdx.x * 128, n0 = blockIdx.y * 128;
  const int wave = tid >> 6, lane = tid & 63;
  const int wm = (wave >> 1) << 6, wn = (wave & 1) << 6;
  const int quad = lane >> 4, l16 = lane & 15;
  const int S = K >> 5, kz = blockIdx.z, KS = gridDim.z;
  const int s0 = (S * kz) / KS, s1 = (S * (kz + 1)) / KS;

  int ra = m0 + (tid >> 2);       if (ra > M - 1) ra = M - 1;
  int ra2 = m0 + 64 + (tid >> 2); if (ra2 > M - 1) ra2 = M - 1;
  int rb = n0 + (tid >> 2);       if (rb > N - 1) rb = N - 1;
  int rb2 = n0 + 64 + (tid >> 2); if (rb2 > N - 1) rb2 = N - 1;
  const u16* Ag  = A + (size_t)ra * lda + (tid & 3) * 8;
  const u16* Ag2 = A + (size_t)ra2 * lda + (tid & 3) * 8;
  const u16* Bg  = Bt + (size_t)rb * ldb + (tid & 3) * 8;
  const u16* Bg2 = Bt + (size_t)rb2 * ldb + (tid & 3) * 8;
  u16* la = lsA + tid * 8;
  u16* lb = lsB + tid * 8;

  f32x4 acc[4][4];
#pragma unroll
  for (int i = 0; i < 4; i++)
#pragma unroll
    for (int j = 0; j < 4; j++) acc[i][j] = (f32x4){0.f, 0.f, 0.f, 0.f};

  for (int s = s0; s < s1; ++s) {
    const int k0 = s << 5;
    __syncthreads();
    gl_lds16(Ag + k0, la);
    gl_lds16(Ag2 + k0, la + 2048);
    gl_lds16(Bg + k0, lb);
    gl_lds16(Bg2 + k0, lb + 2048);
    __syncthreads();
    bf16x8 af[4], bfv[4];
#pragma unroll
    for (int t = 0; t < 4; t++) {
      af[t]  = *(const bf16x8*)(lsA + ((wm + t * 16 + l16) << 5) + (quad << 3));
      bfv[t] = *(const bf16x8*)(lsB + ((wn + t * 16 + l16) << 5) + (quad << 3));
    }
#pragma unroll
    for (int mt = 0; mt < 4; mt++)
#pragma unroll
      for (int nt = 0; nt < 4; nt++)
        acc[mt][nt] = __builtin_amdgcn_mfma_f32_16x16x32_bf16(af[mt], bfv[nt], acc[mt][nt], 0, 0, 0);
  }

#pragma unroll
  for (int mt = 0; mt < 4; mt++)
#pragma unroll
    for (int r = 0; r < 4; r++) {
      const int row = m0 + wm + mt * 16 + quad * 4 + r;
      if (row < M) {
#pragma unroll
        for (int nt = 0; nt < 4; nt++) {
          const int col = n0 + wn + nt * 16 + l16;
          if (col < N) atomicAdd(&outf[(size_t)row * ldc + col], acc[mt][nt][r]);
        }
      }
    }
}

// ---------------- helpers ----------------
__global__ __launch_bounds__(256) void transpose_bf(
    u16* __restrict__ dst, const void* __restrict__ src, int SR, int SC, int DR, int DC,
    const int* __restrict__ flag)
{
  __shared__ u16 t[32][33];
  const int fl = *flag;
  const int tx = threadIdx.x & 31, ty = threadIdx.x >> 5;
  const int j0 = blockIdx.x << 5;
  const int i0 = blockIdx.y << 5;
#pragma unroll
  for (int s = 0; s < 32; s += 8) {
    int sr = j0 + ty + s, sc = i0 + tx;
    u16 v = 0;
    if (sr < SR && sc < SC) {
      size_t idx = (size_t)sr * SC + sc;
      v = fl ? ((const u16*)src)[idx] : f2bf(((const float*)src)[idx]);
    }
    t[ty + s][tx] = v;
  }
  __syncthreads();
#pragma unroll
  for (int s = 0; s < 32; s += 8) {
    int dr = i0 + ty + s, dc = j0 + tx;
    if (dr < DR && dc < DC) dst[(size_t)dr * DC + dc] = t[tx][ty + s];
  }
}

__global__ void build_outT(u16* __restrict__ dst, const void* __restrict__ ow,
                           const int* __restrict__ flag) {
  const int fl = *flag;
  int idx = blockIdx.x * 256 + threadIdx.x;
  if (idx >= 140 * 7264) return;
  int o = idx / 7264, c = idx - o * 7264;
  long si = -1;
  if (c < 3600) si = (long)c * 140 + o;
  else if (c >= 3616 && c < 5416) si = (long)(c - 16) * 140 + o;
  else if (c >= 5440 && c < 7240) si = (long)(c - 40) * 140 + o;
  u16 v = 0;
  if (si >= 0) v = fl ? ((const u16*)ow)[si] : f2bf(((const float*)ow)[si]);
  dst[idx] = v;
}

__global__ void zero_u32(unsigned* p, int n) {
  int i = blockIdx.x * 256 + threadIdx.x;
  if (i < n) p[i] = 0;
}

__global__ void zero_catpads(u16* cat, int rows) {
  int idx = blockIdx.x * 256 + threadIdx.x;
  if (idx >= rows * 64) return;
  int b = idx >> 6, t = idx & 63;
  int col = t < 16 ? 3600 + t : (t < 40 ? 5400 + t : 7200 + t);
  cat[(size_t)b * 7264 + col] = 0;
}

// initialize fp32 output with out_b broadcast
__global__ void init_outf(float* __restrict__ outf, const u16* __restrict__ pbuf) {
  int i = blockIdx.x * 256 + threadIdx.x;
  if (i < 16384 * 140) outf[i] = bf2f(pbuf[P_OB + i % 140]);
}

__device__ __forceinline__ void block_sum2(float& a, float& b, float* red, int t) {
#pragma unroll
  for (int o = 32; o > 0; o >>= 1) { a += __shfl_down(a, o, 64); b += __shfl_down(b, o, 64); }
  __syncthreads();
  if ((t & 63) == 0) { red[t >> 6] = a; red[4 + (t >> 6)] = b; }
  __syncthreads();
  a = red[0] + red[1] + red[2] + red[3];
  b = red[4] + red[5] + red[6] + red[7];
}

__global__ __launch_bounds__(256) void c0_kernel(float* c0, const u16* __restrict__ WoT,
                                                 const u16* __restrict__ pbuf) {
  __shared__ float red[8];
  int d = blockIdx.x, t = threadIdx.x;
  const u16* row = WoT + (size_t)d * 6400;
  const u16* bv = pbuf + P_BV;
  float s = 0.f;
  for (int j = t; j < 6400; j += 256) s += bf2f(bv[j]) * bf2f(row[j]);
  float dummy = 0.f;
  block_sum2(s, dummy, red, t);
  if (t == 0) c0[d] = s + bf2f(pbuf[P_BO + d]);
}

// per row: copy x row into flat; compute enc -> flat[,1200:1600]
__global__ __launch_bounds__(256) void enc_rows(
    const u16* __restrict__ xc, const float* __restrict__ attn,
    const u16* __restrict__ pbuf, u16* __restrict__ flatc, int r0)
{
  __shared__ float red[8];
  const int li = blockIdx.x, t = threadIdx.x;
  const int gr = r0 + li;
  const u16* xr = xc + (size_t)li * 1200;
  u16* fr = flatc + (size_t)li * 1600;
  if (t < 150) ((uint4*)fr)[t] = ((const uint4*)xr)[t];   // cols [0,1200)
  if (gr == 0) {
    if (t < 50) ((uint4*)(fr + 1200))[t] = ((const uint4*)(xr + 800))[t];  // output[0]=x[0,2,:]
    return;
  }
  const u16* xe = xr + 800;
  const float* at = attn + (size_t)li * 400;
  const u16 *g1 = pbuf + P_LN1G, *b1 = pbuf + P_LN1B, *fw1 = pbuf + P_FW1,
            *fb1v = pbuf + P_FB1, *fw2 = pbuf + P_FW2, *fb2v = pbuf + P_FB2,
            *g2 = pbuf + P_LN2G, *b2 = pbuf + P_LN2B;
  const int i1 = t + 256;
  float a0 = bf2f(xe[t]) + at[t];
  float a1 = 0.f;
  if (i1 < 400) a1 = bf2f(xe[i1]) + at[i1];
  float s = a0 + a1, ss = a0 * a0 + a1 * a1;
  block_sum2(s, ss, red, t);
  float mean = s * (1.f / 400.f);
  float var = ss * (1.f / 400.f) - mean * mean;
  float rstd = rsqrtf(var + 1e-6f);
  float o0 = (a0 - mean) * rstd * bf2f(g1[t]) + bf2f(b1[t]);
  float o1 = 0.f;
  if (i1 < 400) o1 = (a1 - mean) * rstd * bf2f(g1[i1]) + bf2f(b1[i1]);
  float d0 = o0 * bf2f(fw1[2 * t]), d1 = o0 * bf2f(fw1[2 * t + 1]);
  if (i1 < 400) { d0 += o1 * bf2f(fw1[2 * i1]); d1 += o1 * bf2f(fw1[2 * i1 + 1]); }
  block_sum2(d0, d1, red, t);
  float t0 = d0 + bf2f(fb1v[0]); t0 = t0 > 0.f ? t0 : 0.f;
  float t1 = d1 + bf2f(fb1v[1]); t1 = t1 > 0.f ? t1 : 0.f;
  float c0v = o0 + t0 * bf2f(fw2[t]) + t1 * bf2f(fw2[400 + t]) + bf2f(fb2v[t]);
  float c1v = 0.f;
  if (i1 < 400) c1v = o1 + t0 * bf2f(fw2[i1]) + t1 * bf2f(fw2[400 + i1]) + bf2f(fb2v[i1]);
  s = c0v + c1v; ss = c0v * c0v + c1v * c1v;
  block_sum2(s, ss, red, t);
  mean = s * (1.f / 400.f);
  var = ss * (1.f / 400.f) - mean * mean;
  rstd = rsqrtf(var + 1e-6f);
  u16* dr = fr + 1200;
  dr[t] = f2bf((c0v - mean) * rstd * bf2f(g2[t]) + bf2f(b2[t]));
  if (i1 < 400) dr[i1] = f2bf((c1v - mean) * rstd * bf2f(g2[i1]) + bf2f(b2[i1]));
}

// GRU nonlinearity: h = (1-sigmoid(xz+bz0+bz1))*elu(xh+bh0 + sigmoid(xr+br0+br1)*bh1)
// ldg parameterized so fwd/bwd halves of a merged [rows x 10800] G can be consumed.
__global__ __launch_bounds__(256) void gru_act(
    const u16* __restrict__ G, int ldg, const u16* __restrict__ pbuf, int boff,
    u16* __restrict__ cat, int off, int rows)
{
  int idx = blockIdx.x * 256 + threadIdx.x;
  if (idx >= rows * 1800) return;
  int b = idx / 1800, u = idx - b * 1800;
  const u16* g = G + (size_t)b * ldg;
  const u16* B = pbuf + boff;
  float xz = bf2f(g[u]) + bf2f(B[u]) + bf2f(B[5400 + u]);
  float xr = bf2f(g[1800 + u]) + bf2f(B[1800 + u]) + bf2f(B[7200 + u]);
  float xh = bf2f(g[3600 + u]) + bf2f(B[3600 + u]);
  float rh = bf2f(B[9000 + u]);
  float z = 1.f / (1.f + expf(-xz));
  float r = 1.f / (1.f + expf(-xr));
  float pre = xh + r * rh;
  float hh = pre > 0.f ? pre : expm1f(pre);
  cat[(size_t)b * 7264 + off + u] = f2bf((1.f - z) * hh);
}

extern "C" void kernel_launch(void* const* d_in, const int* in_sizes, int n_in,
                              void* d_out, int out_size, void* d_ws, size_t ws_size,
                              hipStream_t stream) {
  // Input index maps: dict order (setup_inputs insertion) vs signature order.
  // Disambiguate via in_sizes[15]: dict -> gru_fk (8,640,000), sig -> ln2_g (400).
  static const int MAP_DICT[22] = {5,6,7,8, 9,10,11,12,13,14, 15,17,18,20, 21,22,23,24, 25,26, 27,28};
  static const int MAP_SIG[22]  = {5,6,7,8, 10,11,12,13,14,16, 17,19,20,22, 23,24,25,26, 27,28, 9,15};
  const int* MAP = (in_sizes[15] > 100000) ? MAP_DICT : MAP_SIG;

  const void* x    = d_in[0];
  const void* Wv   = d_in[MAP[0]];
  const void* bv   = d_in[MAP[1]];
  const void* Wo   = d_in[MAP[2]];
  const void* bo   = d_in[MAP[3]];
  const void* ln1b = d_in[MAP[4]];
  const void* fw1  = d_in[MAP[5]];
  const void* fb1  = d_in[MAP[6]];
  const void* fw2  = d_in[MAP[7]];
  const void* fb2  = d_in[MAP[8]];
  const void* ln2b = d_in[MAP[9]];
  const void* gfk  = d_in[MAP[10]];
  const void* gfb  = d_in[MAP[11]];
  const void* gbk  = d_in[MAP[12]];
  const void* gbb  = d_in[MAP[13]];
  const void* d2w  = d_in[MAP[14]];
  const void* d2b  = d_in[MAP[15]];
  const void* d4w  = d_in[MAP[16]];
  const void* d4b  = d_in[MAP[17]];
  const void* ow   = d_in[MAP[18]];
  const void* ob   = d_in[MAP[19]];
  const void* ln1g = d_in[MAP[20]];
  const void* ln2g = d_in[MAP[21]];
  float* outf = (float*)d_out;   // reference output dtype is float32

  unsigned char* base = (unsigned char*)d_ws;
  size_t off = 0;
  auto take = [&](size_t bytes) -> void* {
    void* p = base + off;
    off += (bytes + 255) & ~(size_t)255;
    return p;
  };
  // persistent (~63 MB)
  // NOTE: KfT size 5400*1600*2 = 17,280,000 is 256-aligned, so KbT is exactly
  // contiguous after KfT -> KfT doubles as the merged [10800 x 1600] GRU weight.
  u16*   KfT   = (u16*)take((size_t)5400 * 1600 * 2);
  u16*   KbT   = (u16*)take((size_t)5400 * 1600 * 2);
  u16*   d2T   = (u16*)take((size_t)1800 * 3616 * 2);
  u16*   d4T   = (u16*)take((size_t)1800 * 1824 * 2);
  u16*   outT  = (u16*)take((size_t)140 * 7264 * 2);
  u16*   WoT   = (u16*)take((size_t)400 * 6400 * 2);
  u16*   MT    = (u16*)take((size_t)400 * 416 * 2);
  float* MTf   = (float*)take((size_t)400 * 416 * 4);   // split-K accum for MT
  u16*   pbuf  = (u16*)take((size_t)P_END * 2);
  int*   flag  = (int*)take(256);
  float* c0    = (float*)take(400 * 4);
  float* d2bf  = (float*)take(1800 * 4);
  float* d4bf  = (float*)take(1800 * 4);

  // ---- graduated tier selection: largest chunk CMV whose uniform footprint fits.
  // Per-row bytes (merged-GRU layout): flat 1600 + G 10800 + cat 7264 = 19664 bf16.
  int CMV = 0;
  {
    const size_t avail  = ws_size > off ? ws_size - off : 0;
    const size_t perrow = (size_t)(1600 + 10800 + 7264) * 2;   // 39328 B
    const size_t margin = (size_t)4 << 20;
    if      (avail >= (size_t)16384 * perrow + margin) CMV = 16384;
    else if (avail >= (size_t)8192  * perrow + margin) CMV = 8192;
    else if (avail >= (size_t)4096  * perrow + margin) CMV = 4096;
    else if (avail >= (size_t)2048  * perrow + margin) CMV = 2048;
  }

  u16 *flatc, *Gc, *catc;
  if (CMV) {
    flatc = (u16*)take((size_t)CMV * 1600 * 2);
    Gc    = (u16*)take((size_t)CMV * 10800 * 2);   // merged fwd||bwd gates
    catc  = (u16*)take((size_t)CMV * 7264 * 2);
  } else {
    flatc = (u16*)take((size_t)CM * 1600 * 2);
    Gc    = (u16*)take((size_t)CM * 5400 * 2);
    catc  = (u16*)take((size_t)CM * 7264 * 2);
  }
  const int rows = CMV ? CMV : CM;
  // overlays (lifetimes disjoint): attnc+xc live in Gc before the GRU gemm writes it;
  // Wvc (prep-only) overlays catc before zero_catpads / any cat writes.
  float* attnc = (float*)Gc;                                      // rows*400*4 B
  u16*   xc    = (u16*)((unsigned char*)Gc + (size_t)rows * 1600); // rows*1200*2 B
  u16*   Wvc   = catc;

  // ---- dtype detection + canonicalization ----
  detect_dtype<<<1, 64, 0, stream>>>(flag, x);
  canon_bf<<<2, 256, 0, stream>>>(pbuf + P_LN1G, ln1g, 400, flag);
  canon_bf<<<2, 256, 0, stream>>>(pbuf + P_LN1B, ln1b, 400, flag);
  canon_bf<<<4, 256, 0, stream>>>(pbuf + P_FW1, fw1, 800, flag);
  canon_bf<<<1, 256, 0, stream>>>(pbuf + P_FB1, fb1, 2, flag);
  canon_bf<<<4, 256, 0, stream>>>(pbuf + P_FW2, fw2, 800, flag);
  canon_bf<<<2, 256, 0, stream>>>(pbuf + P_FB2, fb2, 400, flag);
  canon_bf<<<2, 256, 0, stream>>>(pbuf + P_LN2G, ln2g, 400, flag);
  canon_bf<<<2, 256, 0, stream>>>(pbuf + P_LN2B, ln2b, 400, flag);
  canon_bf<<<43, 256, 0, stream>>>(pbuf + P_GFB, gfb, 10800, flag);
  canon_bf<<<43, 256, 0, stream>>>(pbuf + P_GBB, gbb, 10800, flag);
  canon_bf<<<25, 256, 0, stream>>>(pbuf + P_BV, bv, 6400, flag);
  canon_bf<<<2, 256, 0, stream>>>(pbuf + P_BO, bo, 400, flag);
  canon_bf<<<1, 256, 0, stream>>>(pbuf + P_OB, ob, 140, flag);
  canon_f32k<<<8, 256, 0, stream>>>(d2bf, d2b, 1800, flag);
  canon_f32k<<<8, 256, 0, stream>>>(d4bf, d4b, 1800, flag);

  // ---- weight prep ----
  transpose_bf<<<dim3(50, 169), 256, 0, stream>>>(KfT, gfk, 1600, 5400, 5400, 1600, flag);
  transpose_bf<<<dim3(50, 169), 256, 0, stream>>>(KbT, gbk, 1600, 5400, 5400, 1600, flag);
  transpose_bf<<<dim3(113, 57), 256, 0, stream>>>(d2T, d2w, 3600, 1800, 1800, 3616, flag);
  transpose_bf<<<dim3(57, 57), 256, 0, stream>>>(d4T, d4w, 1800, 1800, 1800, 1824, flag);
  transpose_bf<<<dim3(200, 13), 256, 0, stream>>>(WoT, Wo, 6400, 400, 400, 6400, flag);
  build_outT<<<(140 * 7264 + 255) / 256, 256, 0, stream>>>(outT, ow, flag);
  init_outf<<<(16384 * 140 + 255) / 256, 256, 0, stream>>>(outf, pbuf);
  c0_kernel<<<400, 256, 0, stream>>>(c0, WoT, pbuf);

  // MT = (Wv@Wo)^T via split-K (was the single slowest dispatch: 16 blocks, 145 us).
  // 256 blocks, ~13 K-steps each; fp32 atomics into MTf then convert to bf16.
  // (Wvc overlays catc -> must precede x canon / zero_catpads.)
  canon_bf<<<10000, 256, 0, stream>>>(Wvc, Wv, 2560000, flag);
  zero_u32<<<(166400 + 255) / 256, 256, 0, stream>>>((unsigned*)MTf, 166400);
  gemm_bt_sk<<<dim3(4, 4, 16), 256, 0, stream>>>(WoT, Wvc, MTf,
      400, 400, 6400, 6400, 6400, 416);
  f32_to_bf<<<(166400 + 255) / 256, 256, 0, stream>>>(MT, MTf, 166400);

  if (CMV) {
    zero_catpads<<<(CMV * 64 + 255) / 256, 256, 0, stream>>>(catc, CMV);
    const int nchunk = 16384 / CMV;
    for (int c = 0; c < nchunk; ++c) {
      const long r0 = (long)c * CMV;
      canon_x_rows<<<(CMV * 1200 + 255) / 256, 256, 0, stream>>>(
          xc, x, r0 * 1200, CMV * 1200, flag);
      gemm_bt<1, true><<<dim3(CMV / 128, 4), 256, 0, stream>>>(
          xc + 800, MT, attnc, c0, CMV, 400, 416, 1200, 416, 400,
          xc + (size_t)CMV * 1200 - 8);
      enc_rows<<<CMV, 256, 0, stream>>>(xc, attnc, pbuf, flatc, (int)r0);
      // merged GRU (fwd||bwd weights contiguous): N=10800
      gemm_bt<0, false><<<dim3(CMV / 128, 85), 256, 0, stream>>>(
          flatc, KfT, Gc, nullptr, CMV, 10800, 1600, 1600, 1600, 10800, nullptr);
      gru_act<<<(CMV * 1800 + 255) / 256, 256, 0, stream>>>(
          Gc, 10800, pbuf, P_GFB, catc, 0, CMV);
      gru_act<<<(CMV * 1800 + 255) / 256, 256, 0, stream>>>(
          Gc + 5400, 10800, pbuf, P_GBB, catc, 1800, CMV);
      gemm_bt<2, false><<<dim3(CMV / 128, 15), 256, 0, stream>>>(
          catc, d2T, catc + 3616, d2bf, CMV, 1800, 3616, 7264, 3616, 7264, nullptr);
      gemm_bt<2, false><<<dim3(CMV / 128, 15), 256, 0, stream>>>(
          catc + 3616, d4T, catc + 5440, d4bf, CMV, 1800, 1824, 7264, 1824, 7264, nullptr);
      gemm_bt_sk<<<dim3(CMV / 128, 2, 8), 256, 0, stream>>>(
          catc, outT, outf + (size_t)r0 * 140, CMV, 140, 7264, 7264, 7264, 140);
    }
  } else {
    // fallback: previously verified per-chunk path (non-merged GRU)
    zero_catpads<<<(CM * 64 + 255) / 256, 256, 0, stream>>>(catc, CM);
    for (int c = 0; c < NC; ++c) {
      const int r0 = c * CM;
      canon_x_rows<<<(CM * 1200 + 255) / 256, 256, 0, stream>>>(
          xc, x, (long)r0 * 1200, CM * 1200, flag);
      gemm_bt<1, true><<<dim3(CM / 128, 4), 256, 0, stream>>>(
          xc + 800, MT, attnc, c0, CM, 400, 416, 1200, 416, 400,
          xc + (size_t)CM * 1200 - 8);
      enc_rows<<<CM, 256, 0, stream>>>(xc, attnc, pbuf, flatc, r0);
      gemm_bt<0, false><<<dim3(CM / 128, 43), 256, 0, stream>>>(
          flatc, KfT, Gc, nullptr, CM, 5400, 1600, 1600, 1600, 5400, nullptr);
      gru_act<<<(CM * 1800 + 255) / 256, 256, 0, stream>>>(
          Gc, 5400, pbuf, P_GFB, catc, 0, CM);
      gemm_bt<0, false><<<dim3(CM / 128, 43), 256, 0, stream>>>(
          flatc, KbT, Gc, nullptr, CM, 5400, 1600, 1600, 1600, 5400, nullptr);
      gru_act<<<(CM * 1800 + 255) / 256, 256, 0, stream>>>(
          Gc, 5400, pbuf, P_GBB, catc, 1800, CM);
      gemm_bt<2, false><<<dim3(CM / 128, 15), 256, 0, stream>>>(
          catc, d2T, catc + 3616, d2bf, CM, 1800, 3616, 7264, 3616, 7264, nullptr);
      gemm_bt<2, false><<<dim3(CM / 128, 15), 256, 0, stream>>>(
          catc + 3616, d4T, catc + 5440, d4bf, CM, 1800, 1824, 7264, 1824, 7264, nullptr);
      gemm_bt_sk<<<dim3(CM / 128, 2, 8), 256, 0, stream>>>(
          catc, outT, outf + (size_t)r0 * 140, CM, 140, 7264, 7264, 7264, 140);
    }
  }
}

// Round 3
// 2281.661 us; speedup vs baseline: 1.5017x; 1.0716x over previous
//
#include <hip/hip_runtime.h>
#include <hip/hip_bf16.h>

typedef unsigned short u16;
using bf16x8 = __attribute__((ext_vector_type(8))) short;
using f32x4  = __attribute__((ext_vector_type(4))) float;

#define CM 2048   // fallback chunk rows
#define NC 8      // fallback chunks (CM*NC = 16384)

// pbuf offsets (canonical bf16 small params)
#define P_LN1G 0
#define P_LN1B 400
#define P_FW1  800
#define P_FB1  1600
#define P_FW2  1602
#define P_FB2  2402
#define P_LN2G 2802
#define P_LN2B 3202
#define P_GFB  3602
#define P_GBB  14402
#define P_BV   25202
#define P_BO   31602
#define P_OB   32002
#define P_END  32142

__device__ __forceinline__ u16 f2bf(float f) {
  unsigned u = __float_as_uint(f);
  unsigned r = u + 0x7FFFu + ((u >> 16) & 1u);   // RNE
  return (u16)(r >> 16);
}
__device__ __forceinline__ float bf2f(u16 h) {
  return __uint_as_float(((unsigned)h) << 16);
}

__device__ __forceinline__ void gl_lds16(const u16* g, u16* l) {
  __builtin_amdgcn_global_load_lds(
      (__attribute__((address_space(1))) void*)g,
      (__attribute__((address_space(3))) void*)l, 16, 0, 0);
}

// ---- runtime input-dtype detection: flag=1 if bf16, 0 if fp32 ----
__global__ void detect_dtype(int* flag, const void* x) {
  if (threadIdx.x == 0 && blockIdx.x == 0) {
    const u16* p = (const u16*)x;
    int cnt = 0;
    for (int i = 0; i < 64; i++) {
      int e = (p[2 * i] >> 7) & 0xFF;
      if (e >= 0x70 && e <= 0x85) cnt++;
    }
    *flag = (cnt >= 32) ? 1 : 0;
  }
}

__global__ void canon_bf(u16* __restrict__ dst, const void* __restrict__ src,
                         int n, const int* __restrict__ flag) {
  int i = blockIdx.x * 256 + threadIdx.x;
  if (i >= n) return;
  dst[i] = (*flag) ? ((const u16*)src)[i] : f2bf(((const float*)src)[i]);
}

__global__ void canon_x_rows(u16* __restrict__ dst, const void* __restrict__ src,
                             long base, int n, const int* __restrict__ flag) {
  int i = blockIdx.x * 256 + threadIdx.x;
  if (i >= n) return;
  long j = base + i;
  dst[i] = (*flag) ? ((const u16*)src)[j] : f2bf(((const float*)src)[j]);
}

__global__ void canon_f32k(float* __restrict__ dst, const void* __restrict__ src,
                           int n, const int* __restrict__ flag) {
  int i = blockIdx.x * 256 + threadIdx.x;
  if (i >= n) return;
  dst[i] = (*flag) ? bf2f(((const u16*)src)[i]) : ((const float*)src)[i];
}

__global__ void f32_to_bf(u16* __restrict__ dst, const float* __restrict__ src, int n) {
  int i = blockIdx.x * 256 + threadIdx.x;
  if (i < n) dst[i] = f2bf(src[i]);
}

// ---------------- generic bf16 GEMM: C(MxN) = A(MxK) @ Bt(NxK)^T ----------------
// EPI: 0 = store bf16(acc); 1 = store f32(acc + bias[col]); 2 = store bf16(elu(acc + bias[col]))
// CL: clamp A global pointers to aend (K-pad reads near buffer end; clamped data finite, x0)
template <int EPI, bool CL>
__global__ __launch_bounds__(256) void gemm_bt(
    const u16* __restrict__ A, const u16* __restrict__ Bt, void* __restrict__ Cv,
    const float* __restrict__ bias, int M, int N, int K, int lda, int ldb, int ldc,
    const u16* aend)
{
  __shared__ u16 lsA[128 * 32];
  __shared__ u16 lsB[128 * 32];
  const int tid = threadIdx.x;
  const int m0 = blockIdx.x * 128, n0 = blockIdx.y * 128;
  const int wave = tid >> 6, lane = tid & 63;
  const int wm = (wave >> 1) << 6, wn = (wave & 1) << 6;
  const int quad = lane >> 4, l16 = lane & 15;

  int ra = m0 + (tid >> 2);       if (ra > M - 1) ra = M - 1;
  int ra2 = m0 + 64 + (tid >> 2); if (ra2 > M - 1) ra2 = M - 1;
  int rb = n0 + (tid >> 2);       if (rb > N - 1) rb = N - 1;
  int rb2 = n0 + 64 + (tid >> 2); if (rb2 > N - 1) rb2 = N - 1;
  const u16* Ag  = A + (size_t)ra * lda + (tid & 3) * 8;
  const u16* Ag2 = A + (size_t)ra2 * lda + (tid & 3) * 8;
  const u16* Bg  = Bt + (size_t)rb * ldb + (tid & 3) * 8;
  const u16* Bg2 = Bt + (size_t)rb2 * ldb + (tid & 3) * 8;
  u16* la = lsA + tid * 8;
  u16* lb = lsB + tid * 8;

  f32x4 acc[4][4];
#pragma unroll
  for (int i = 0; i < 4; i++)
#pragma unroll
    for (int j = 0; j < 4; j++) acc[i][j] = (f32x4){0.f, 0.f, 0.f, 0.f};

  for (int k0 = 0; k0 < K; k0 += 32) {
    __syncthreads();
    const u16* pa  = Ag + k0;
    const u16* pa2 = Ag2 + k0;
    if (CL) { if (pa > aend) pa = aend; if (pa2 > aend) pa2 = aend; }
    gl_lds16(pa, la);
    gl_lds16(pa2, la + 2048);
    gl_lds16(Bg + k0, lb);
    gl_lds16(Bg2 + k0, lb + 2048);
    __syncthreads();
    bf16x8 af[4], bfv[4];
#pragma unroll
    for (int t = 0; t < 4; t++) {
      af[t]  = *(const bf16x8*)(lsA + ((wm + t * 16 + l16) << 5) + (quad << 3));
      bfv[t] = *(const bf16x8*)(lsB + ((wn + t * 16 + l16) << 5) + (quad << 3));
    }
#pragma unroll
    for (int mt = 0; mt < 4; mt++)
#pragma unroll
      for (int nt = 0; nt < 4; nt++)
        acc[mt][nt] = __builtin_amdgcn_mfma_f32_16x16x32_bf16(af[mt], bfv[nt], acc[mt][nt], 0, 0, 0);
  }

#pragma unroll
  for (int mt = 0; mt < 4; mt++)
#pragma unroll
    for (int r = 0; r < 4; r++) {
      const int row = m0 + wm + mt * 16 + quad * 4 + r;
      if (row < M) {
#pragma unroll
        for (int nt = 0; nt < 4; nt++) {
          const int col = n0 + wn + nt * 16 + l16;
          if (col < N) {
            float v = acc[mt][nt][r];
            if (EPI == 0) ((u16*)Cv)[(size_t)row * ldc + col] = f2bf(v);
            if (EPI == 1) ((float*)Cv)[(size_t)row * ldc + col] = v + bias[col];
            if (EPI == 2) {
              float p = v + bias[col];
              ((u16*)Cv)[(size_t)row * ldc + col] = f2bf(p > 0.f ? p : expm1f(p));
            }
          }
        }
      }
    }
}

// ---------------- 256x256 8-wave double-buffered GEMM (T2+T3+T4+T5) ----------------
// C(MxN) = A(MxK) @ Bt(NxK)^T, K % 64 == 0. 512 threads, 128 KiB LDS, 1 block/CU.
// LDS tiles are [256 rows][64 cols] bf16 (128 B rows); the 16B-chunk index is
// XOR-swizzled by (row&7) on BOTH the global_load_lds source (linear LDS dest,
// rule #21) and the ds_read address -> b128 reads hit the 8-access/bank floor.
// Pipeline: prefetch next K-tile into buf^1, then s_waitcnt vmcnt(8) (counted:
// waits only for current tile's 8 loads), raw s_barrier (no __syncthreads ->
// no vmcnt(0) drain). setprio(1) around each 32-MFMA cluster.
template <int EPI>
__global__ __launch_bounds__(512, 2) void gemm256_bt(
    const u16* __restrict__ A, const u16* __restrict__ Bt, void* __restrict__ Cv,
    const float* __restrict__ bias, int M, int N, int K, int lda, int ldb, int ldc)
{
  __shared__ u16 lds8[65536];            // 2 bufs x (A 16384 + B 16384) u16
  const int tid = threadIdx.x;
  const int m0 = blockIdx.x * 256, n0 = blockIdx.y * 256;
  const int wave = tid >> 6, lane = tid & 63;
  const int wm = (wave >> 2) * 128;      // wave row base: waves 0-3 -> 0, 4-7 -> 128
  const int wn = (wave & 3) * 64;        // wave col base
  const int quad = lane >> 4, l16 = lane & 15;

  // staging map: per gl_lds instr, 64 rows x 8 chunks of 16B; thread t covers
  // dest (row = t>>3, chunk = t&7); source chunk pre-swizzled by ^(row&7).
  const int srow = tid >> 3;
  const int sblk = ((tid & 7) ^ (srow & 7)) * 8;   // u16 offset of source chunk
  const u16* Ag[4];
  const u16* Bg[4];
#pragma unroll
  for (int i = 0; i < 4; i++) {
    int raw = m0 + i * 64 + srow; if (raw > M - 1) raw = M - 1;
    int rbw = n0 + i * 64 + srow; if (rbw > N - 1) rbw = N - 1;
    Ag[i] = A  + (size_t)raw * lda + sblk;
    Bg[i] = Bt + (size_t)rbw * ldb + sblk;
  }

  f32x4 acc[8][4];
#pragma unroll
  for (int i = 0; i < 8; i++)
#pragma unroll
    for (int j = 0; j < 4; j++) acc[i][j] = (f32x4){0.f, 0.f, 0.f, 0.f};

  const int nT = K >> 6;
  // prologue: stage K-tile 0 into buf 0
#pragma unroll
  for (int i = 0; i < 4; i++) gl_lds16(Ag[i], lds8 + i * 4096 + tid * 8);
#pragma unroll
  for (int i = 0; i < 4; i++) gl_lds16(Bg[i], lds8 + 16384 + i * 4096 + tid * 8);

  int c = 0;
  for (int t = 0; t < nT; ++t) {
    __builtin_amdgcn_s_barrier();        // all waves done reading buf[c^1]
    if (t + 1 < nT) {
      const int k1 = (t + 1) << 6;
      u16* dst = lds8 + (c ^ 1) * 32768;
#pragma unroll
      for (int i = 0; i < 4; i++) gl_lds16(Ag[i] + k1, dst + i * 4096 + tid * 8);
#pragma unroll
      for (int i = 0; i < 4; i++) gl_lds16(Bg[i] + k1, dst + 16384 + i * 4096 + tid * 8);
      asm volatile("s_waitcnt vmcnt(8)" ::: "memory");   // tile t landed (8 newer in flight)
    } else {
      asm volatile("s_waitcnt vmcnt(0)" ::: "memory");
    }
    __builtin_amdgcn_s_barrier();        // tile t staged for ALL waves
    const u16* lA = lds8 + c * 32768;
    const u16* lB = lA + 16384;
#pragma unroll
    for (int kk = 0; kk < 2; kk++) {
      const int ch = kk * 4 + quad;
      bf16x8 af[8], bv[4];
#pragma unroll
      for (int mt = 0; mt < 8; mt++)
        af[mt] = *(const bf16x8*)(lA + (wm + mt * 16 + l16) * 64 + ((ch ^ (l16 & 7)) * 8));
#pragma unroll
      for (int nt = 0; nt < 4; nt++)
        bv[nt] = *(const bf16x8*)(lB + (wn + nt * 16 + l16) * 64 + ((ch ^ (l16 & 7)) * 8));
      __builtin_amdgcn_s_setprio(1);
#pragma unroll
      for (int mt = 0; mt < 8; mt++)
#pragma unroll
        for (int nt = 0; nt < 4; nt++)
          acc[mt][nt] = __builtin_amdgcn_mfma_f32_16x16x32_bf16(af[mt], bv[nt], acc[mt][nt], 0, 0, 0);
      __builtin_amdgcn_s_setprio(0);
    }
    c ^= 1;
  }

#pragma unroll
  for (int mt = 0; mt < 8; mt++)
#pragma unroll
    for (int r = 0; r < 4; r++) {
      const int row = m0 + wm + mt * 16 + quad * 4 + r;
      if (row < M) {
#pragma unroll
        for (int nt = 0; nt < 4; nt++) {
          const int col = n0 + wn + nt * 16 + l16;
          if (col < N) {
            float v = acc[mt][nt][r];
            if (EPI == 0) ((u16*)Cv)[(size_t)row * ldc + col] = f2bf(v);
            if (EPI == 2) {
              float p = v + bias[col];
              ((u16*)Cv)[(size_t)row * ldc + col] = f2bf(p > 0.f ? p : expm1f(p));
            }
          }
        }
      }
    }
}

// ---- split-K GEMM, fp32 atomicAdd into pre-initialized float output ----
__global__ __launch_bounds__(256) void gemm_bt_sk(
    const u16* __restrict__ A, const u16* __restrict__ Bt, float* __restrict__ outf,
    int M, int N, int K, int lda, int ldb, int ldc)
{
  __shared__ u16 lsA[128 * 32];
  __shared__ u16 lsB[128 * 32];
  const int tid = threadIdx.x;
  const int m0 = blockIdx.x * 128, n0 = blockIdx.y * 128;
  const int wave = tid >> 6, lane = tid & 63;
  const int wm = (wave >> 1) << 6, wn = (wave & 1) << 6;
  const int quad = lane >> 4, l16 = lane & 15;
  const int S = K >> 5, kz = blockIdx.z, KS = gridDim.z;
  const int s0 = (S * kz) / KS, s1 = (S * (kz + 1)) / KS;

  int ra = m0 + (tid >> 2);       if (ra > M - 1) ra = M - 1;
  int ra2 = m0 + 64 + (tid >> 2); if (ra2 > M - 1) ra2 = M - 1;
  int rb = n0 + (tid >> 2);       if (rb > N - 1) rb = N - 1;
  int rb2 = n0 + 64 + (tid >> 2); if (rb2 > N - 1) rb2 = N - 1;
  const u16* Ag  = A + (size_t)ra * lda + (tid & 3) * 8;
  const u16* Ag2 = A + (size_t)ra2 * lda + (tid & 3) * 8;
  const u16* Bg  = Bt + (size_t)rb * ldb + (tid & 3) * 8;
  const u16* Bg2 = Bt + (size_t)rb2 * ldb + (tid & 3) * 8;
  u16* la = lsA + tid * 8;
  u16* lb = lsB + tid * 8;

  f32x4 acc[4][4];
#pragma unroll
  for (int i = 0; i < 4; i++)
#pragma unroll
    for (int j = 0; j < 4; j++) acc[i][j] = (f32x4){0.f, 0.f, 0.f, 0.f};

  for (int s = s0; s < s1; ++s) {
    const int k0 = s << 5;
    __syncthreads();
    gl_lds16(Ag + k0, la);
    gl_lds16(Ag2 + k0, la + 2048);
    gl_lds16(Bg + k0, lb);
    gl_lds16(Bg2 + k0, lb + 2048);
    __syncthreads();
    bf16x8 af[4], bfv[4];
#pragma unroll
    for (int t = 0; t < 4; t++) {
      af[t]  = *(const bf16x8*)(lsA + ((wm + t * 16 + l16) << 5) + (quad << 3));
      bfv[t] = *(const bf16x8*)(lsB + ((wn + t * 16 + l16) << 5) + (quad << 3));
    }
#pragma unroll
    for (int mt = 0; mt < 4; mt++)
#pragma unroll
      for (int nt = 0; nt < 4; nt++)
        acc[mt][nt] = __builtin_amdgcn_mfma_f32_16x16x32_bf16(af[mt], bfv[nt], acc[mt][nt], 0, 0, 0);
  }

#pragma unroll
  for (int mt = 0; mt < 4; mt++)
#pragma unroll
    for (int r = 0; r < 4; r++) {
      const int row = m0 + wm + mt * 16 + quad * 4 + r;
      if (row < M) {
#pragma unroll
        for (int nt = 0; nt < 4; nt++) {
          const int col = n0 + wn + nt * 16 + l16;
          if (col < N) atomicAdd(&outf[(size_t)row * ldc + col], acc[mt][nt][r]);
        }
      }
    }
}

// ---------------- helpers ----------------
__global__ __launch_bounds__(256) void transpose_bf(
    u16* __restrict__ dst, const void* __restrict__ src, int SR, int SC, int DR, int DC,
    const int* __restrict__ flag)
{
  __shared__ u16 t[32][33];
  const int fl = *flag;
  const int tx = threadIdx.x & 31, ty = threadIdx.x >> 5;
  const int j0 = blockIdx.x << 5;
  const int i0 = blockIdx.y << 5;
#pragma unroll
  for (int s = 0; s < 32; s += 8) {
    int sr = j0 + ty + s, sc = i0 + tx;
    u16 v = 0;
    if (sr < SR && sc < SC) {
      size_t idx = (size_t)sr * SC + sc;
      v = fl ? ((const u16*)src)[idx] : f2bf(((const float*)src)[idx]);
    }
    t[ty + s][tx] = v;
  }
  __syncthreads();
#pragma unroll
  for (int s = 0; s < 32; s += 8) {
    int dr = i0 + ty + s, dc = j0 + tx;
    if (dr < DR && dc < DC) dst[(size_t)dr * DC + dc] = t[tx][ty + s];
  }
}

__global__ void build_outT(u16* __restrict__ dst, const void* __restrict__ ow,
                           const int* __restrict__ flag) {
  const int fl = *flag;
  int idx = blockIdx.x * 256 + threadIdx.x;
  if (idx >= 140 * 7264) return;
  int o = idx / 7264, c = idx - o * 7264;
  long si = -1;
  if (c < 3600) si = (long)c * 140 + o;
  else if (c >= 3616 && c < 5416) si = (long)(c - 16) * 140 + o;
  else if (c >= 5440 && c < 7240) si = (long)(c - 40) * 140 + o;
  u16 v = 0;
  if (si >= 0) v = fl ? ((const u16*)ow)[si] : f2bf(((const float*)ow)[si]);
  dst[idx] = v;
}

__global__ void zero_u32(unsigned* p, int n) {
  int i = blockIdx.x * 256 + threadIdx.x;
  if (i < n) p[i] = 0;
}

__global__ void zero_catpads(u16* cat, int rows) {
  int idx = blockIdx.x * 256 + threadIdx.x;
  if (idx >= rows * 64) return;
  int b = idx >> 6, t = idx & 63;
  int col = t < 16 ? 3600 + t : (t < 40 ? 5400 + t : 7200 + t);
  cat[(size_t)b * 7264 + col] = 0;
}

// initialize fp32 output with out_b broadcast
__global__ void init_outf(float* __restrict__ outf, const u16* __restrict__ pbuf) {
  int i = blockIdx.x * 256 + threadIdx.x;
  if (i < 16384 * 140) outf[i] = bf2f(pbuf[P_OB + i % 140]);
}

__device__ __forceinline__ void block_sum2(float& a, float& b, float* red, int t) {
#pragma unroll
  for (int o = 32; o > 0; o >>= 1) { a += __shfl_down(a, o, 64); b += __shfl_down(b, o, 64); }
  __syncthreads();
  if ((t & 63) == 0) { red[t >> 6] = a; red[4 + (t >> 6)] = b; }
  __syncthreads();
  a = red[0] + red[1] + red[2] + red[3];
  b = red[4] + red[5] + red[6] + red[7];
}

__global__ __launch_bounds__(256) void c0_kernel(float* c0, const u16* __restrict__ WoT,
                                                 const u16* __restrict__ pbuf) {
  __shared__ float red[8];
  int d = blockIdx.x, t = threadIdx.x;
  const u16* row = WoT + (size_t)d * 6400;
  const u16* bv = pbuf + P_BV;
  float s = 0.f;
  for (int j = t; j < 6400; j += 256) s += bf2f(bv[j]) * bf2f(row[j]);
  float dummy = 0.f;
  block_sum2(s, dummy, red, t);
  if (t == 0) c0[d] = s + bf2f(pbuf[P_BO + d]);
}

// per row: copy x row into flat; compute enc -> flat[,1200:1600]
__global__ __launch_bounds__(256) void enc_rows(
    const u16* __restrict__ xc, const float* __restrict__ attn,
    const u16* __restrict__ pbuf, u16* __restrict__ flatc, int r0)
{
  __shared__ float red[8];
  const int li = blockIdx.x, t = threadIdx.x;
  const int gr = r0 + li;
  const u16* xr = xc + (size_t)li * 1200;
  u16* fr = flatc + (size_t)li * 1600;
  if (t < 150) ((uint4*)fr)[t] = ((const uint4*)xr)[t];   // cols [0,1200)
  if (gr == 0) {
    if (t < 50) ((uint4*)(fr + 1200))[t] = ((const uint4*)(xr + 800))[t];  // output[0]=x[0,2,:]
    return;
  }
  const u16* xe = xr + 800;
  const float* at = attn + (size_t)li * 400;
  const u16 *g1 = pbuf + P_LN1G, *b1 = pbuf + P_LN1B, *fw1 = pbuf + P_FW1,
            *fb1v = pbuf + P_FB1, *fw2 = pbuf + P_FW2, *fb2v = pbuf + P_FB2,
            *g2 = pbuf + P_LN2G, *b2 = pbuf + P_LN2B;
  const int i1 = t + 256;
  float a0 = bf2f(xe[t]) + at[t];
  float a1 = 0.f;
  if (i1 < 400) a1 = bf2f(xe[i1]) + at[i1];
  float s = a0 + a1, ss = a0 * a0 + a1 * a1;
  block_sum2(s, ss, red, t);
  float mean = s * (1.f / 400.f);
  float var = ss * (1.f / 400.f) - mean * mean;
  float rstd = rsqrtf(var + 1e-6f);
  float o0 = (a0 - mean) * rstd * bf2f(g1[t]) + bf2f(b1[t]);
  float o1 = 0.f;
  if (i1 < 400) o1 = (a1 - mean) * rstd * bf2f(g1[i1]) + bf2f(b1[i1]);
  float d0 = o0 * bf2f(fw1[2 * t]), d1 = o0 * bf2f(fw1[2 * t + 1]);
  if (i1 < 400) { d0 += o1 * bf2f(fw1[2 * i1]); d1 += o1 * bf2f(fw1[2 * i1 + 1]); }
  block_sum2(d0, d1, red, t);
  float t0 = d0 + bf2f(fb1v[0]); t0 = t0 > 0.f ? t0 : 0.f;
  float t1 = d1 + bf2f(fb1v[1]); t1 = t1 > 0.f ? t1 : 0.f;
  float c0v = o0 + t0 * bf2f(fw2[t]) + t1 * bf2f(fw2[400 + t]) + bf2f(fb2v[t]);
  float c1v = 0.f;
  if (i1 < 400) c1v = o1 + t0 * bf2f(fw2[i1]) + t1 * bf2f(fw2[400 + i1]) + bf2f(fb2v[i1]);
  s = c0v + c1v; ss = c0v * c0v + c1v * c1v;
  block_sum2(s, ss, red, t);
  mean = s * (1.f / 400.f);
  var = ss * (1.f / 400.f) - mean * mean;
  rstd = rsqrtf(var + 1e-6f);
  u16* dr = fr + 1200;
  dr[t] = f2bf((c0v - mean) * rstd * bf2f(g2[t]) + bf2f(b2[t]));
  if (i1 < 400) dr[i1] = f2bf((c1v - mean) * rstd * bf2f(g2[i1]) + bf2f(b2[i1]));
}

// GRU nonlinearity: h = (1-sigmoid(xz+bz0+bz1))*elu(xh+bh0 + sigmoid(xr+br0+br1)*bh1)
// ldg parameterized so fwd/bwd halves of a merged [rows x 10800] G can be consumed.
__global__ __launch_bounds__(256) void gru_act(
    const u16* __restrict__ G, int ldg, const u16* __restrict__ pbuf, int boff,
    u16* __restrict__ cat, int off, int rows)
{
  int idx = blockIdx.x * 256 + threadIdx.x;
  if (idx >= rows * 1800) return;
  int b = idx / 1800, u = idx - b * 1800;
  const u16* g = G + (size_t)b * ldg;
  const u16* B = pbuf + boff;
  float xz = bf2f(g[u]) + bf2f(B[u]) + bf2f(B[5400 + u]);
  float xr = bf2f(g[1800 + u]) + bf2f(B[1800 + u]) + bf2f(B[7200 + u]);
  float xh = bf2f(g[3600 + u]) + bf2f(B[3600 + u]);
  float rh = bf2f(B[9000 + u]);
  float z = 1.f / (1.f + expf(-xz));
  float r = 1.f / (1.f + expf(-xr));
  float pre = xh + r * rh;
  float hh = pre > 0.f ? pre : expm1f(pre);
  cat[(size_t)b * 7264 + off + u] = f2bf((1.f - z) * hh);
}

extern "C" void kernel_launch(void* const* d_in, const int* in_sizes, int n_in,
                              void* d_out, int out_size, void* d_ws, size_t ws_size,
                              hipStream_t stream) {
  // Input index maps: dict order (setup_inputs insertion) vs signature order.
  // Disambiguate via in_sizes[15]: dict -> gru_fk (8,640,000), sig -> ln2_g (400).
  static const int MAP_DICT[22] = {5,6,7,8, 9,10,11,12,13,14, 15,17,18,20, 21,22,23,24, 25,26, 27,28};
  static const int MAP_SIG[22]  = {5,6,7,8, 10,11,12,13,14,16, 17,19,20,22, 23,24,25,26, 27,28, 9,15};
  const int* MAP = (in_sizes[15] > 100000) ? MAP_DICT : MAP_SIG;

  const void* x    = d_in[0];
  const void* Wv   = d_in[MAP[0]];
  const void* bv   = d_in[MAP[1]];
  const void* Wo   = d_in[MAP[2]];
  const void* bo   = d_in[MAP[3]];
  const void* ln1b = d_in[MAP[4]];
  const void* fw1  = d_in[MAP[5]];
  const void* fb1  = d_in[MAP[6]];
  const void* fw2  = d_in[MAP[7]];
  const void* fb2  = d_in[MAP[8]];
  const void* ln2b = d_in[MAP[9]];
  const void* gfk  = d_in[MAP[10]];
  const void* gfb  = d_in[MAP[11]];
  const void* gbk  = d_in[MAP[12]];
  const void* gbb  = d_in[MAP[13]];
  const void* d2w  = d_in[MAP[14]];
  const void* d2b  = d_in[MAP[15]];
  const void* d4w  = d_in[MAP[16]];
  const void* d4b  = d_in[MAP[17]];
  const void* ow   = d_in[MAP[18]];
  const void* ob   = d_in[MAP[19]];
  const void* ln1g = d_in[MAP[20]];
  const void* ln2g = d_in[MAP[21]];
  float* outf = (float*)d_out;   // reference output dtype is float32

  unsigned char* base = (unsigned char*)d_ws;
  size_t off = 0;
  auto take = [&](size_t bytes) -> void* {
    void* p = base + off;
    off += (bytes + 255) & ~(size_t)255;
    return p;
  };
  // persistent (~63 MB)
  // NOTE: KfT size 5400*1600*2 = 17,280,000 is 256-aligned, so KbT is exactly
  // contiguous after KfT -> KfT doubles as the merged [10800 x 1600] GRU weight.
  u16*   KfT   = (u16*)take((size_t)5400 * 1600 * 2);
  u16*   KbT   = (u16*)take((size_t)5400 * 1600 * 2);
  u16*   d2T   = (u16*)take((size_t)1800 * 3616 * 2);
  u16*   d4T   = (u16*)take((size_t)1800 * 1824 * 2);
  u16*   outT  = (u16*)take((size_t)140 * 7264 * 2);
  u16*   WoT   = (u16*)take((size_t)400 * 6400 * 2);
  u16*   MT    = (u16*)take((size_t)400 * 416 * 2);
  float* MTf   = (float*)take((size_t)400 * 416 * 4);   // split-K accum for MT
  u16*   pbuf  = (u16*)take((size_t)P_END * 2);
  int*   flag  = (int*)take(256);
  float* c0    = (float*)take(400 * 4);
  float* d2bf  = (float*)take(1800 * 4);
  float* d4bf  = (float*)take(1800 * 4);

  // ---- graduated tier selection: largest chunk CMV whose uniform footprint fits.
  // Per-row bytes (merged-GRU layout): flat 1600 + G 10800 + cat 7264 = 19664 bf16.
  int CMV = 0;
  {
    const size_t avail  = ws_size > off ? ws_size - off : 0;
    const size_t perrow = (size_t)(1600 + 10800 + 7264) * 2;   // 39328 B
    const size_t margin = (size_t)4 << 20;
    if      (avail >= (size_t)16384 * perrow + margin) CMV = 16384;
    else if (avail >= (size_t)8192  * perrow + margin) CMV = 8192;
    else if (avail >= (size_t)4096  * perrow + margin) CMV = 4096;
    else if (avail >= (size_t)2048  * perrow + margin) CMV = 2048;
  }

  u16 *flatc, *Gc, *catc;
  if (CMV) {
    flatc = (u16*)take((size_t)CMV * 1600 * 2);
    Gc    = (u16*)take((size_t)CMV * 10800 * 2);   // merged fwd||bwd gates
    catc  = (u16*)take((size_t)CMV * 7264 * 2);
  } else {
    flatc = (u16*)take((size_t)CM * 1600 * 2);
    Gc    = (u16*)take((size_t)CM * 5400 * 2);
    catc  = (u16*)take((size_t)CM * 7264 * 2);
  }
  const int rows = CMV ? CMV : CM;
  // overlays (lifetimes disjoint): attnc+xc live in Gc before the GRU gemm writes it;
  // Wvc (prep-only) overlays catc before zero_catpads / any cat writes.
  float* attnc = (float*)Gc;                                      // rows*400*4 B
  u16*   xc    = (u16*)((unsigned char*)Gc + (size_t)rows * 1600); // rows*1200*2 B
  u16*   Wvc   = catc;

  // ---- dtype detection + canonicalization ----
  detect_dtype<<<1, 64, 0, stream>>>(flag, x);
  canon_bf<<<2, 256, 0, stream>>>(pbuf + P_LN1G, ln1g, 400, flag);
  canon_bf<<<2, 256, 0, stream>>>(pbuf + P_LN1B, ln1b, 400, flag);
  canon_bf<<<4, 256, 0, stream>>>(pbuf + P_FW1, fw1, 800, flag);
  canon_bf<<<1, 256, 0, stream>>>(pbuf + P_FB1, fb1, 2, flag);
  canon_bf<<<4, 256, 0, stream>>>(pbuf + P_FW2, fw2, 800, flag);
  canon_bf<<<2, 256, 0, stream>>>(pbuf + P_FB2, fb2, 400, flag);
  canon_bf<<<2, 256, 0, stream>>>(pbuf + P_LN2G, ln2g, 400, flag);
  canon_bf<<<2, 256, 0, stream>>>(pbuf + P_LN2B, ln2b, 400, flag);
  canon_bf<<<43, 256, 0, stream>>>(pbuf + P_GFB, gfb, 10800, flag);
  canon_bf<<<43, 256, 0, stream>>>(pbuf + P_GBB, gbb, 10800, flag);
  canon_bf<<<25, 256, 0, stream>>>(pbuf + P_BV, bv, 6400, flag);
  canon_bf<<<2, 256, 0, stream>>>(pbuf + P_BO, bo, 400, flag);
  canon_bf<<<1, 256, 0, stream>>>(pbuf + P_OB, ob, 140, flag);
  canon_f32k<<<8, 256, 0, stream>>>(d2bf, d2b, 1800, flag);
  canon_f32k<<<8, 256, 0, stream>>>(d4bf, d4b, 1800, flag);

  // ---- weight prep ----
  transpose_bf<<<dim3(50, 169), 256, 0, stream>>>(KfT, gfk, 1600, 5400, 5400, 1600, flag);
  transpose_bf<<<dim3(50, 169), 256, 0, stream>>>(KbT, gbk, 1600, 5400, 5400, 1600, flag);
  transpose_bf<<<dim3(113, 57), 256, 0, stream>>>(d2T, d2w, 3600, 1800, 1800, 3616, flag);
  transpose_bf<<<dim3(57, 57), 256, 0, stream>>>(d4T, d4w, 1800, 1800, 1800, 1824, flag);
  transpose_bf<<<dim3(200, 13), 256, 0, stream>>>(WoT, Wo, 6400, 400, 400, 6400, flag);
  build_outT<<<(140 * 7264 + 255) / 256, 256, 0, stream>>>(outT, ow, flag);
  init_outf<<<(16384 * 140 + 255) / 256, 256, 0, stream>>>(outf, pbuf);
  c0_kernel<<<400, 256, 0, stream>>>(c0, WoT, pbuf);

  // MT = (Wv@Wo)^T via split-K; fp32 atomics into MTf then convert to bf16.
  // (Wvc overlays catc -> must precede x canon / zero_catpads.)
  canon_bf<<<10000, 256, 0, stream>>>(Wvc, Wv, 2560000, flag);
  zero_u32<<<(166400 + 255) / 256, 256, 0, stream>>>((unsigned*)MTf, 166400);
  gemm_bt_sk<<<dim3(4, 4, 16), 256, 0, stream>>>(WoT, Wvc, MTf,
      400, 400, 6400, 6400, 6400, 416);
  f32_to_bf<<<(166400 + 255) / 256, 256, 0, stream>>>(MT, MTf, 166400);

  if (CMV) {
    zero_catpads<<<(CMV * 64 + 255) / 256, 256, 0, stream>>>(catc, CMV);
    const int nchunk = 16384 / CMV;
    for (int c = 0; c < nchunk; ++c) {
      const long r0 = (long)c * CMV;
      canon_x_rows<<<(CMV * 1200 + 255) / 256, 256, 0, stream>>>(
          xc, x, r0 * 1200, CMV * 1200, flag);
      gemm_bt<1, true><<<dim3(CMV / 128, 4), 256, 0, stream>>>(
          xc + 800, MT, attnc, c0, CMV, 400, 416, 1200, 416, 400,
          xc + (size_t)CMV * 1200 - 8);
      enc_rows<<<CMV, 256, 0, stream>>>(xc, attnc, pbuf, flatc, (int)r0);
      // merged GRU (fwd||bwd weights contiguous): 256^2 8-wave pipelined kernel
      gemm256_bt<0><<<dim3(CMV / 256, 43), 512, 0, stream>>>(
          flatc, KfT, Gc, nullptr, CMV, 10800, 1600, 1600, 1600, 10800);
      gru_act<<<(CMV * 1800 + 255) / 256, 256, 0, stream>>>(
          Gc, 10800, pbuf, P_GFB, catc, 0, CMV);
      gru_act<<<(CMV * 1800 + 255) / 256, 256, 0, stream>>>(
          Gc + 5400, 10800, pbuf, P_GBB, catc, 1800, CMV);
      gemm_bt<2, false><<<dim3(CMV / 128, 15), 256, 0, stream>>>(
          catc, d2T, catc + 3616, d2bf, CMV, 1800, 3616, 7264, 3616, 7264, nullptr);
      gemm_bt<2, false><<<dim3(CMV / 128, 15), 256, 0, stream>>>(
          catc + 3616, d4T, catc + 5440, d4bf, CMV, 1800, 1824, 7264, 1824, 7264, nullptr);
      gemm_bt_sk<<<dim3(CMV / 128, 2, 8), 256, 0, stream>>>(
          catc, outT, outf + (size_t)r0 * 140, CMV, 140, 7264, 7264, 7264, 140);
    }
  } else {
    // fallback: previously verified per-chunk path (non-merged GRU, 128^2 only)
    zero_catpads<<<(CM * 64 + 255) / 256, 256, 0, stream>>>(catc, CM);
    for (int c = 0; c < NC; ++c) {
      const int r0 = c * CM;
      canon_x_rows<<<(CM * 1200 + 255) / 256, 256, 0, stream>>>(
          xc, x, (long)r0 * 1200, CM * 1200, flag);
      gemm_bt<1, true><<<dim3(CM / 128, 4), 256, 0, stream>>>(
          xc + 800, MT, attnc, c0, CM, 400, 416, 1200, 416, 400,
          xc + (size_t)CM * 1200 - 8);
      enc_rows<<<CM, 256, 0, stream>>>(xc, attnc, pbuf, flatc, r0);
      gemm_bt<0, false><<<dim3(CM / 128, 43), 256, 0, stream>>>(
          flatc, KfT, Gc, nullptr, CM, 5400, 1600, 1600, 1600, 5400, nullptr);
      gru_act<<<(CM * 1800 + 255) / 256, 256, 0, stream>>>(
          Gc, 5400, pbuf, P_GFB, catc, 0, CM);
      gemm_bt<0, false><<<dim3(CM / 128, 43), 256, 0, stream>>>(
          flatc, KbT, Gc, nullptr, CM, 5400, 1600, 1600, 1600, 5400, nullptr);
      gru_act<<<(CM * 1800 + 255) / 256, 256, 0, stream>>>(
          Gc, 5400, pbuf, P_GBB, catc, 1800, CM);
      gemm_bt<2, false><<<dim3(CM / 128, 15), 256, 0, stream>>>(
          catc, d2T, catc + 3616, d2bf, CM, 1800, 3616, 7264, 3616, 7264, nullptr);
      gemm_bt<2, false><<<dim3(CM / 128, 15), 256, 0, stream>>>(
          catc + 3616, d4T, catc + 5440, d4bf, CM, 1800, 1824, 7264, 1824, 7264, nullptr);
      gemm_bt_sk<<<dim3(CM / 128, 2, 8), 256, 0, stream>>>(
          catc, outT, outf + (size_t)r0 * 140, CM, 140, 7264, 7264, 7264, 140);
    }
  }
}